// Round 13
// baseline (153.711 us; speedup 1.0000x reference)
//
#include <hip/hip_runtime.h>

#define HW    16384   // 128*128
#define Wh    128
#define Cin   64
#define C2    32
#define HW4   4096    // 64*64

typedef short short8 __attribute__((ext_vector_type(8)));     // 8 bf16 = 4 VGPRs
typedef float float4v __attribute__((ext_vector_type(4)));
typedef unsigned uint4v __attribute__((ext_vector_type(4)));

#define LOG2E 1.44269504f
#define OFFE  43.2808512f   // 30*log2(e): exp(s-30) == exp2(s*log2e - OFFE)

__device__ __forceinline__ unsigned pack2bf16(float lo, float hi) {
  unsigned ul = __builtin_bit_cast(unsigned, lo);
  unsigned uh = __builtin_bit_cast(unsigned, hi);
  ul = (ul + 0x7fffu + ((ul >> 16) & 1u)) >> 16;
  uh = (uh + 0x7fffu + ((uh >> 16) & 1u)) & 0xffff0000u;
  return ul | uh;
}
__device__ __forceinline__ unsigned short f2bf(float f) {
  unsigned u = __builtin_bit_cast(unsigned, f);
  return (unsigned short)((u + 0x7fffu + ((u >> 16) & 1u)) >> 16);
}
// RTZ-truncate two fp32 to bf16, lo in [15:0], hi in [31:16]
__device__ __forceinline__ unsigned packtrunc(float lo, float hi) {
  return __builtin_amdgcn_perm(__builtin_bit_cast(unsigned, hi),
                               __builtin_bit_cast(unsigned, lo), 0x07060302u);
}

// ---------------------------------------------------------------------------
// Kernel 0: weight repack. wAll[og][c][24] = {theta(8, x log2e), phi(8), g(8)}
// ---------------------------------------------------------------------------
__global__ __launch_bounds__(256) void repack_w_kern(
    const float* __restrict__ wt, const float* __restrict__ bt,
    const float* __restrict__ wp, const float* __restrict__ bp,
    const float* __restrict__ wg, const float* __restrict__ bg,
    float* __restrict__ wAll, float* __restrict__ bAll) {
  int idx = blockIdx.x * 256 + threadIdx.x;
  if (idx < 6144) {
    int og = idx / 1536, rem = idx % 1536;
    int c = rem / 24, j = rem % 24;
    int o = og * 8 + (j & 7);
    float v;
    if (j < 8)       v = wt[o * Cin + c] * LOG2E;
    else if (j < 16) v = wp[o * Cin + c];
    else             v = wg[o * Cin + c];
    wAll[idx] = v;
  } else if (idx < 6240) {
    int i2 = idx - 6144;
    int og = i2 / 24, j = i2 % 24;
    int o = og * 8 + (j & 7);
    bAll[i2] = (j < 8) ? bt[o] * LOG2E : (j < 16 ? bp[o] : bg[o]);
  }
}

// ---------------------------------------------------------------------------
// Kernel 1: FUSED theta+phi+g conv (+2x2 maxpool) — R0 form; V store is
// TILE-MAJOR (R24 layout): Vt[bz][tile][ch][key_in_tile]. Unchanged.
// ---------------------------------------------------------------------------
__global__ __launch_bounds__(256) void conv_qkv_kern(
    const float* __restrict__ x, const float* __restrict__ wAll,
    const float* __restrict__ bAll, unsigned short* __restrict__ Q,
    unsigned short* __restrict__ K, unsigned short* __restrict__ Vt) {
  __shared__ float smX[2][8][256];               // 16 KB, double-buffered
  __shared__ unsigned short smV[8][64];          // 1 KB
  int tid = threadIdx.x;
  int og = blockIdx.y, bz = blockIdx.z;
  int pxbase = blockIdx.x * 2 * Wh;              // full-res rows 2i, 2i+1
  int jloc = tid >> 2;                           // pooled col 0..63
  int rpar = (tid >> 1) & 1, cpar = tid & 1;
  int myPx = rpar * Wh + 2 * jloc + cpar;        // local pixel 0..255
  const float* xb = x + (size_t)bz * Cin * HW + pxbase;
  const float* wc = wAll + og * 1536;            // uniform -> s_load
  const float* bb = bAll + og * 24;

  // stage chunk: 512 float4 = 256 threads x 2; ch = f>>6, p4 = f&63
  auto stage = [&](int cb8, int buf) {
#pragma unroll
    for (int u = 0; u < 2; ++u) {
      int f = u * 256 + tid;
      int ch = f >> 6, p4 = f & 63;
      *(float4*)&smX[buf][ch][p4 * 4] =
          *(const float4*)(xb + (size_t)(cb8 * 8 + ch) * HW + p4 * 4);
    }
  };

  float acc[24];
#pragma unroll
  for (int k = 0; k < 24; ++k) acc[k] = bb[k];

  stage(0, 0);
  __syncthreads();
  for (int cb8 = 0; cb8 < 8; ++cb8) {
    if (cb8 < 7) stage(cb8 + 1, (cb8 + 1) & 1);  // loads fly over compute
    float xv[8];
#pragma unroll
    for (int u = 0; u < 8; ++u) xv[u] = smX[cb8 & 1][u][myPx];
#pragma unroll
    for (int u = 0; u < 8; ++u) {
#pragma unroll
      for (int k = 0; k < 24; ++k)
        acc[k] = fmaf(wc[(cb8 * 8 + u) * 24 + k], xv[u], acc[k]);
    }
    __syncthreads();                             // staged buf ready for next
  }

  int pp = blockIdx.x * 64 + jloc;               // global pooled pixel
  int p = pxbase + myPx;                         // global full-res pixel
  // theta -> Q
  {
    uint4 up;
    up.x = pack2bf16(acc[0], acc[1]); up.y = pack2bf16(acc[2], acc[3]);
    up.z = pack2bf16(acc[4], acc[5]); up.w = pack2bf16(acc[6], acc[7]);
    *(uint4*)(Q + ((size_t)bz * HW + p) * C2 + og * 8) = up;
  }
  // 2x2 maxpool across lane-mates {4j..4j+3}
  float aP[8], aG[8];
#pragma unroll
  for (int o = 0; o < 8; ++o) {
    float vp = acc[8 + o], vg = acc[16 + o];
    vp = fmaxf(vp, __shfl_xor(vp, 1)); vp = fmaxf(vp, __shfl_xor(vp, 2));
    vg = fmaxf(vg, __shfl_xor(vg, 1)); vg = fmaxf(vg, __shfl_xor(vg, 2));
    aP[o] = vp; aG[o] = vg;
  }
  if ((tid & 3) == 0) {
    int loc = pp & 31, tile = pp >> 5;
    int prow = ((loc & 4) << 2) + ((loc >> 3) << 2) + (loc & 3);   // S^T perm
    uint4 up;
    up.x = pack2bf16(aP[0], aP[1]); up.y = pack2bf16(aP[2], aP[3]);
    up.z = pack2bf16(aP[4], aP[5]); up.w = pack2bf16(aP[6], aP[7]);
    *(uint4*)(K + ((size_t)bz * HW4 + tile * 32 + prow) * C2 + og * 8) = up;
#pragma unroll
    for (int o = 0; o < 8; ++o) smV[o][tid >> 2] = f2bf(aG[o]);
  }
  __syncthreads();
  // V store, TILE-MAJOR: Vt[bz][tile][ch][kin]. thread t -> ch t>>5,
  // keys 2*(t&31), 2*(t&31)+1 (one dword, same tile). Wave = two 128 B
  // segments -> coalesced.
  {
    int ch = tid >> 5, idx = tid & 31;
    unsigned v = ((unsigned*)smV)[ch * 32 + idx];
    int tile = blockIdx.x * 2 + (idx >> 4);      // key64 = 2*idx
    int kin = (2 * idx) & 31;
    *(unsigned*)(Vt + (size_t)bz * C2 * HW4 + (size_t)tile * (C2 * 32) +
                 (size_t)(og * 8 + ch) * 32 + kin) = v;
  }
}

// ---------------------------------------------------------------------------
// Kernel 2: MFMA flash attention — R27: QROWS=128 (8 fragments/wave).
// Validated 3-point model: wall/SIMD = ~45k cyc (MFMA-pipe fixed) +
// ~137 cyc x loads/SIMD (R24: 512->115k=48.2µs; R25: 1024->185k=77µs;
// R26: 512@8waves->121k=50.5µs; wave count irrelevant). Loads are already
// maximally wide (1 KB/wave-load) -> only knob left: amortize each K/V
// tile-visit over MORE Q-rows. QROWS 64->128 halves loads/SIMD to 256:
// predicted wall max(VALU 54k, 45k) + 137*256 ~= 89k ~= 37 µs.
// Cost: 8 fragments -> ~180 VGPR -> 2 waves/SIMD (VGPR-forced). R26
// showed 8->4 waves free; this bets 4->2 is tolerable given 8 independent
// fragment chains/tile of intra-wave ILP. (256,2) -> 256-reg cap, no
// spill expected. LDS 51.5 KB x 2 blocks/CU = 103 <= 160.
// Same key-quarter split + same merge association -> bitwise-identical.
// Tripwires: WRITE_SIZE >> 8.2 MB = spill; attn > 50 µs = 2-wave
// occupancy collapse -> revert R24 and accept plateau.
// ---------------------------------------------------------------------------
__global__ __launch_bounds__(256, 2) void attn_mfma_kern(
    const unsigned short* __restrict__ Qb, const unsigned short* __restrict__ Kb,
    const unsigned short* __restrict__ Vt, float* __restrict__ Y) {
  __shared__ float smY[3][128][33];   // 50.7 KB
  __shared__ float smL[4][128];       // 2 KB
  int lane = threadIdx.x & 63;
  int wv = threadIdx.x >> 6;
  int quad = lane >> 4, l16 = lane & 15;
  int bz = blockIdx.y;
  int qrow0 = blockIdx.x * 128;

  short8 qf[8];
#pragma unroll
  for (int f = 0; f < 8; ++f)
    qf[f] = *(const short8*)(Qb + ((size_t)bz * HW + qrow0 + f * 16 + l16) * C2 + quad * 8);
  const unsigned short* kb = Kb + ((size_t)bz * HW4 + wv * 1024) * C2;
  // wave wv's quarter = tiles wv*32 .. wv*32+31; one tile = C2*32 = 1024 shorts
  const unsigned short* vb = Vt + (size_t)bz * C2 * HW4 + (size_t)(wv * 32) * 1024;

  short8 ones;
#pragma unroll
  for (int i = 0; i < 8; ++i) ones[i] = (short)0x3F80;  // bf16 1.0

  float4v z = {0.f, 0.f, 0.f, 0.f};
  float4v ya[8] = {z, z, z, z, z, z, z, z};   // y cols l16 (ch 0..15)
  float4v yh[8] = {z, z, z, z, z, z, z, z};   // y cols 16+l16
  float4v y2[8] = {z, z, z, z, z, z, z, z};   // row sums l (ones-MFMA)
  float4v moff = {-OFFE, -OFFE, -OFFE, -OFFE};

  for (int t = 0; t < 32; ++t) {
    const unsigned short* kt = kb + (size_t)t * 32 * C2;
    const unsigned short* vt = vb + (size_t)t * 1024;
    short8 ka = *(const short8*)(kt + (size_t)l16 * C2 + quad * 8);
    short8 kh = *(const short8*)(kt + (size_t)(16 + l16) * C2 + quad * 8);
    short8 va = *(const short8*)(vt + l16 * 32 + quad * 8);          // 1 KB contig
    short8 vh = *(const short8*)(vt + (16 + l16) * 32 + quad * 8);   // next 1 KB
#pragma unroll
    for (int f = 0; f < 8; ++f) {
      float4v sa = __builtin_amdgcn_mfma_f32_16x16x32_bf16(ka, qf[f], moff, 0, 0, 0);
      float4v sh = __builtin_amdgcn_mfma_f32_16x16x32_bf16(kh, qf[f], moff, 0, 0, 0);
      float e0 = __builtin_amdgcn_exp2f(sa[0]), e1 = __builtin_amdgcn_exp2f(sa[1]);
      float e2 = __builtin_amdgcn_exp2f(sa[2]), e3 = __builtin_amdgcn_exp2f(sa[3]);
      float g0 = __builtin_amdgcn_exp2f(sh[0]), g1 = __builtin_amdgcn_exp2f(sh[1]);
      float g2 = __builtin_amdgcn_exp2f(sh[2]), g3 = __builtin_amdgcn_exp2f(sh[3]);
      uint4v d = {packtrunc(e0, e1), packtrunc(e2, e3),
                  packtrunc(g0, g1), packtrunc(g2, g3)};
      short8 pf = __builtin_bit_cast(short8, d);
      ya[f] = __builtin_amdgcn_mfma_f32_16x16x32_bf16(pf, va,   ya[f], 0, 0, 0);
      yh[f] = __builtin_amdgcn_mfma_f32_16x16x32_bf16(pf, vh,   yh[f], 0, 0, 0);
      y2[f] = __builtin_amdgcn_mfma_f32_16x16x32_bf16(pf, ones, y2[f], 0, 0, 0);
    }
  }

  // merge the 4 key quarters (R0 epilogue pattern, 8 fragments)
  if (l16 == 0) {
#pragma unroll
    for (int f = 0; f < 8; ++f)
#pragma unroll
      for (int r = 0; r < 4; ++r)
        smL[wv][f * 16 + quad * 4 + r] = y2[f][r];   // cols identical
  }
  if (wv > 0) {
    int pi = wv - 1;
#pragma unroll
    for (int f = 0; f < 8; ++f)
#pragma unroll
      for (int r = 0; r < 4; ++r) {
        int lr = f * 16 + quad * 4 + r;
        smY[pi][lr][l16] = ya[f][r];
        smY[pi][lr][16 + l16] = yh[f][r];
      }
  }
  __syncthreads();
  if (wv == 0) {
#pragma unroll
    for (int f = 0; f < 8; ++f)
#pragma unroll
      for (int r = 0; r < 4; ++r) {
        int lr = f * 16 + quad * 4 + r;
        float a0 = ya[f][r] + smY[0][lr][l16] + smY[1][lr][l16] + smY[2][lr][l16];
        float a1 = yh[f][r] + smY[0][lr][16 + l16] + smY[1][lr][16 + l16] + smY[2][lr][16 + l16];
        float L = smL[0][lr] + smL[1][lr] + smL[2][lr] + smL[3][lr];
        float inv = 1.f / L;
        size_t rw = (size_t)bz * HW + qrow0 + lr;
        Y[rw * C2 + l16] = a0 * inv;
        Y[rw * C2 + 16 + l16] = a1 * inv;
      }
  }
}

// ---------------------------------------------------------------------------
// Kernel 3: output conv (32->64) + bias + residual — EXACT R4 version
// (best measured; R21 LDS staging regressed). cog split x8, 2048 blocks.
// ---------------------------------------------------------------------------
__global__ __launch_bounds__(256) void conv_out_kern(
    const float* __restrict__ Y, const float* __restrict__ x,
    const float* __restrict__ w, const float* __restrict__ bias,
    float* __restrict__ out) {
  int p = blockIdx.x * 256 + threadIdx.x;
  int cog = blockIdx.y, bz = blockIdx.z;    // cog 0..7 -> channels cog*8..+7
  const float* xb = x + (size_t)bz * Cin * HW + p;
  float xr[8];
#pragma unroll
  for (int i = 0; i < 8; ++i)               // residual loads in flight
    xr[i] = xb[(size_t)(cog * 8 + i) * HW];
  float y[C2];
  const float4* yp4 = (const float4*)(Y + ((size_t)bz * HW + p) * C2);
#pragma unroll
  for (int i = 0; i < 8; ++i) {
    float4 t = yp4[i];
    y[4 * i] = t.x; y[4 * i + 1] = t.y; y[4 * i + 2] = t.z; y[4 * i + 3] = t.w;
  }
  float* ob = out + (size_t)bz * Cin * HW + p;
#pragma unroll
  for (int i = 0; i < 8; ++i) {
    int co = cog * 8 + i;
    float s = bias[co];
#pragma unroll
    for (int o = 0; o < C2; ++o) s = fmaf(w[co * C2 + o], y[o], s);  // s_load
    ob[(size_t)co * HW] = s + xr[i];
  }
}

// ---------------------------------------------------------------------------
extern "C" void kernel_launch(void* const* d_in, const int* in_sizes, int n_in,
                              void* d_out, int out_size, void* d_ws, size_t ws_size,
                              hipStream_t stream) {
  const float* x       = (const float*)d_in[0];
  const float* w_theta = (const float*)d_in[1];
  const float* b_theta = (const float*)d_in[2];
  const float* w_phi   = (const float*)d_in[3];
  const float* b_phi   = (const float*)d_in[4];
  const float* w_g     = (const float*)d_in[5];
  const float* b_g     = (const float*)d_in[6];
  const float* w_out   = (const float*)d_in[7];
  const float* b_out   = (const float*)d_in[8];
  float* out = (float*)d_out;

  float* Yws = (float*)d_ws;                                   // 8 MB fp32
  unsigned short* Qb = (unsigned short*)(Yws + (size_t)4 * HW * C2);
  unsigned short* Kb = Qb + (size_t)4 * HW * C2;
  unsigned short* Vt = Kb + (size_t)4 * HW4 * C2;
  float* wAll = (float*)(Vt + (size_t)4 * HW4 * C2);           // 6144 f
  float* bAll = wAll + 6144;                                   // 96 f

  repack_w_kern<<<25, 256, 0, stream>>>(w_theta, b_theta, w_phi, b_phi,
                                        w_g, b_g, wAll, bAll);
  conv_qkv_kern<<<dim3(64, 4, 4), 256, 0, stream>>>(x, wAll, bAll, Qb, Kb, Vt);
  attn_mfma_kern<<<dim3(HW / 128, 4), 256, 0, stream>>>(Qb, Kb, Vt, Yws);
  conv_out_kern<<<dim3(64, 8, 4), 256, 0, stream>>>(Yws, x, w_out, b_out, out);
}

// Round 14
// 152.602 us; speedup vs baseline: 1.0073x; 1.0073x over previous
//
#include <hip/hip_runtime.h>

#define HW    16384   // 128*128
#define Wh    128
#define Cin   64
#define C2    32
#define HW4   4096    // 64*64

typedef short short8 __attribute__((ext_vector_type(8)));     // 8 bf16 = 4 VGPRs
typedef float float4v __attribute__((ext_vector_type(4)));
typedef unsigned uint4v __attribute__((ext_vector_type(4)));

#define LOG2E 1.44269504f
#define OFFE  43.2808512f   // 30*log2(e): exp(s-30) == exp2(s*log2e - OFFE)

__device__ __forceinline__ unsigned pack2bf16(float lo, float hi) {
  unsigned ul = __builtin_bit_cast(unsigned, lo);
  unsigned uh = __builtin_bit_cast(unsigned, hi);
  ul = (ul + 0x7fffu + ((ul >> 16) & 1u)) >> 16;
  uh = (uh + 0x7fffu + ((uh >> 16) & 1u)) & 0xffff0000u;
  return ul | uh;
}
__device__ __forceinline__ unsigned short f2bf(float f) {
  unsigned u = __builtin_bit_cast(unsigned, f);
  return (unsigned short)((u + 0x7fffu + ((u >> 16) & 1u)) >> 16);
}
// RTZ-truncate two fp32 to bf16, lo in [15:0], hi in [31:16]
__device__ __forceinline__ unsigned packtrunc(float lo, float hi) {
  return __builtin_amdgcn_perm(__builtin_bit_cast(unsigned, hi),
                               __builtin_bit_cast(unsigned, lo), 0x07060302u);
}

// ---------------------------------------------------------------------------
// Kernel 0: weight repack. wAll[og][c][24] = {theta(8, x log2e), phi(8), g(8)}
// (layout unchanged; og8 conv blocks index halves of each og group)
// ---------------------------------------------------------------------------
__global__ __launch_bounds__(256) void repack_w_kern(
    const float* __restrict__ wt, const float* __restrict__ bt,
    const float* __restrict__ wp, const float* __restrict__ bp,
    const float* __restrict__ wg, const float* __restrict__ bg,
    float* __restrict__ wAll, float* __restrict__ bAll) {
  int idx = blockIdx.x * 256 + threadIdx.x;
  if (idx < 6144) {
    int og = idx / 1536, rem = idx % 1536;
    int c = rem / 24, j = rem % 24;
    int o = og * 8 + (j & 7);
    float v;
    if (j < 8)       v = wt[o * Cin + c] * LOG2E;
    else if (j < 16) v = wp[o * Cin + c];
    else             v = wg[o * Cin + c];
    wAll[idx] = v;
  } else if (idx < 6240) {
    int i2 = idx - 6144;
    int og = i2 / 24, j = i2 % 24;
    int o = og * 8 + (j & 7);
    bAll[i2] = (j < 8) ? bt[o] * LOG2E : (j < 16 ? bp[o] : bg[o]);
  }
}

// ---------------------------------------------------------------------------
// Kernel 1: FUSED theta+phi+g conv (+2x2 maxpool) — R28: OG-SPLIT x8.
// Ledger: F(fixed harness overhead) + conv_qkv ~= 87 µs with conv_qkv <= 48
// (never in top-5); Dispatch_Id spacing shows ~11 harness reset dispatches
// per iteration -> F ~= 35-65 is untouchable. This probe decides which:
// if conv_qkv is latency-bloated (s_load weight batches ~250 cyc with only
// 104 SGPRs -> reloads per cb8, 8 lockstep barriers, only 4 waves/SIMD
// grid-capped), doubling occupancy fixes it. Each block now computes 4
// channels of each of theta/phi/g (acc[12]); grid (64,8,4) = 2048 blocks
// = 8 blocks/CU = 8 waves/SIMD; (256,8) caps VGPR at 64 >> ~40 live (no
// spill, unlike attn's 74-live R2 case). Per-output FMA chain order
// unchanged -> bitwise-identical Q/K/V. Staging doubles (~12% of issue);
// total FMA issue unchanged.
// ---------------------------------------------------------------------------
__global__ __launch_bounds__(256, 8) void conv_qkv_kern(
    const float* __restrict__ x, const float* __restrict__ wAll,
    const float* __restrict__ bAll, unsigned short* __restrict__ Q,
    unsigned short* __restrict__ K, unsigned short* __restrict__ Vt) {
  __shared__ float smX[2][8][256];               // 16 KB, double-buffered
  __shared__ unsigned short smV[4][64];          // 0.5 KB
  int tid = threadIdx.x;
  int og4 = blockIdx.y, bz = blockIdx.z;         // og4 0..7 -> 4 ch each
  int og = og4 >> 1, half = og4 & 1;
  int pxbase = blockIdx.x * 2 * Wh;              // full-res rows 2i, 2i+1
  int jloc = tid >> 2;                           // pooled col 0..63
  int rpar = (tid >> 1) & 1, cpar = tid & 1;
  int myPx = rpar * Wh + 2 * jloc + cpar;        // local pixel 0..255
  const float* xb = x + (size_t)bz * Cin * HW + pxbase;
  const float* wc = wAll + og * 1536;            // uniform -> s_load
  const float* bb = bAll + og * 24;

  // stage chunk: 512 float4 = 256 threads x 2; ch = f>>6, p4 = f&63
  auto stage = [&](int cb8, int buf) {
#pragma unroll
    for (int u = 0; u < 2; ++u) {
      int f = u * 256 + tid;
      int ch = f >> 6, p4 = f & 63;
      *(float4*)&smX[buf][ch][p4 * 4] =
          *(const float4*)(xb + (size_t)(cb8 * 8 + ch) * HW + p4 * 4);
    }
  };

  // acc[0..3]=theta, [4..7]=phi, [8..11]=g for channels og*8 + half*4 + jj
  float acc[12];
#pragma unroll
  for (int s = 0; s < 3; ++s)
#pragma unroll
    for (int jj = 0; jj < 4; ++jj)
      acc[s * 4 + jj] = bb[s * 8 + half * 4 + jj];

  stage(0, 0);
  __syncthreads();
  for (int cb8 = 0; cb8 < 8; ++cb8) {
    if (cb8 < 7) stage(cb8 + 1, (cb8 + 1) & 1);  // loads fly over compute
    float xv[8];
#pragma unroll
    for (int u = 0; u < 8; ++u) xv[u] = smX[cb8 & 1][u][myPx];
#pragma unroll
    for (int u = 0; u < 8; ++u) {
#pragma unroll
      for (int s = 0; s < 3; ++s)
#pragma unroll
        for (int jj = 0; jj < 4; ++jj)
          acc[s * 4 + jj] = fmaf(wc[(cb8 * 8 + u) * 24 + s * 8 + half * 4 + jj],
                                 xv[u], acc[s * 4 + jj]);
    }
    __syncthreads();                             // staged buf ready for next
  }

  int pp = blockIdx.x * 64 + jloc;               // global pooled pixel
  int p = pxbase + myPx;                         // global full-res pixel
  // theta -> Q (4 bf16 = uint2, 8 B aligned)
  {
    uint2 up;
    up.x = pack2bf16(acc[0], acc[1]); up.y = pack2bf16(acc[2], acc[3]);
    *(uint2*)(Q + ((size_t)bz * HW + p) * C2 + og4 * 4) = up;
  }
  // 2x2 maxpool across lane-mates {4j..4j+3}
  float aP[4], aG[4];
#pragma unroll
  for (int o = 0; o < 4; ++o) {
    float vp = acc[4 + o], vg = acc[8 + o];
    vp = fmaxf(vp, __shfl_xor(vp, 1)); vp = fmaxf(vp, __shfl_xor(vp, 2));
    vg = fmaxf(vg, __shfl_xor(vg, 1)); vg = fmaxf(vg, __shfl_xor(vg, 2));
    aP[o] = vp; aG[o] = vg;
  }
  if ((tid & 3) == 0) {
    int loc = pp & 31, tile = pp >> 5;
    int prow = ((loc & 4) << 2) + ((loc >> 3) << 2) + (loc & 3);   // S^T perm
    uint2 up;
    up.x = pack2bf16(aP[0], aP[1]); up.y = pack2bf16(aP[2], aP[3]);
    *(uint2*)(K + ((size_t)bz * HW4 + tile * 32 + prow) * C2 + og4 * 4) = up;
#pragma unroll
    for (int o = 0; o < 4; ++o) smV[o][tid >> 2] = f2bf(aG[o]);
  }
  __syncthreads();
  // V store, TILE-MAJOR: Vt[bz][tile][ch][kin]; 128 threads, 1 dword each
  if (tid < 128) {
    int ch = tid >> 5, idx = tid & 31;
    unsigned v = ((unsigned*)smV)[ch * 32 + idx];
    int tile = blockIdx.x * 2 + (idx >> 4);      // key64 = 2*idx
    int kin = (2 * idx) & 31;
    *(unsigned*)(Vt + (size_t)bz * C2 * HW4 + (size_t)tile * (C2 * 32) +
                 (size_t)(og4 * 4 + ch) * 32 + kin) = v;
  }
}

// ---------------------------------------------------------------------------
// Kernel 2: MFMA flash attention — EXACT R24 form (best measured: 48.2 µs).
// attn surgery closed: loads 512->1024 hurts 1.6x (R25), 512->256 neutral
// (R27), waves 2/4/8 all equal (R27/R24/R26), 6 scheduling probes neutral.
// Tile-major V (the one real win, +11 µs) retained.
// ---------------------------------------------------------------------------
__global__ __launch_bounds__(256, 4) void attn_mfma_kern(
    const unsigned short* __restrict__ Qb, const unsigned short* __restrict__ Kb,
    const unsigned short* __restrict__ Vt, float* __restrict__ Y) {
  __shared__ float smY[3][64][33];   // 25.3 KB
  __shared__ float smL[4][64];       // 1 KB
  int lane = threadIdx.x & 63;
  int wv = threadIdx.x >> 6;
  int quad = lane >> 4, l16 = lane & 15;
  int bz = blockIdx.y;
  int qrow0 = blockIdx.x * 64;

  short8 qf[4];
#pragma unroll
  for (int f = 0; f < 4; ++f)
    qf[f] = *(const short8*)(Qb + ((size_t)bz * HW + qrow0 + f * 16 + l16) * C2 + quad * 8);
  const unsigned short* kb = Kb + ((size_t)bz * HW4 + wv * 1024) * C2;
  // wave wv's quarter = tiles wv*32 .. wv*32+31; one tile = C2*32 = 1024 shorts
  const unsigned short* vb = Vt + (size_t)bz * C2 * HW4 + (size_t)(wv * 32) * 1024;

  short8 ones;
#pragma unroll
  for (int i = 0; i < 8; ++i) ones[i] = (short)0x3F80;  // bf16 1.0

  float4v z = {0.f, 0.f, 0.f, 0.f};
  float4v ya[4] = {z, z, z, z};   // y cols l16 (ch 0..15)
  float4v yh[4] = {z, z, z, z};   // y cols 16+l16
  float4v y2[4] = {z, z, z, z};   // row sums l (ones-MFMA)
  float4v moff = {-OFFE, -OFFE, -OFFE, -OFFE};

  for (int t = 0; t < 32; ++t) {
    const unsigned short* kt = kb + (size_t)t * 32 * C2;
    const unsigned short* vt = vb + (size_t)t * 1024;
    short8 ka = *(const short8*)(kt + (size_t)l16 * C2 + quad * 8);
    short8 kh = *(const short8*)(kt + (size_t)(16 + l16) * C2 + quad * 8);
    short8 va = *(const short8*)(vt + l16 * 32 + quad * 8);          // 1 KB contig
    short8 vh = *(const short8*)(vt + (16 + l16) * 32 + quad * 8);   // next 1 KB
#pragma unroll
    for (int f = 0; f < 4; ++f) {
      float4v sa = __builtin_amdgcn_mfma_f32_16x16x32_bf16(ka, qf[f], moff, 0, 0, 0);
      float4v sh = __builtin_amdgcn_mfma_f32_16x16x32_bf16(kh, qf[f], moff, 0, 0, 0);
      float e0 = __builtin_amdgcn_exp2f(sa[0]), e1 = __builtin_amdgcn_exp2f(sa[1]);
      float e2 = __builtin_amdgcn_exp2f(sa[2]), e3 = __builtin_amdgcn_exp2f(sa[3]);
      float g0 = __builtin_amdgcn_exp2f(sh[0]), g1 = __builtin_amdgcn_exp2f(sh[1]);
      float g2 = __builtin_amdgcn_exp2f(sh[2]), g3 = __builtin_amdgcn_exp2f(sh[3]);
      uint4v d = {packtrunc(e0, e1), packtrunc(e2, e3),
                  packtrunc(g0, g1), packtrunc(g2, g3)};
      short8 pf = __builtin_bit_cast(short8, d);
      ya[f] = __builtin_amdgcn_mfma_f32_16x16x32_bf16(pf, va,   ya[f], 0, 0, 0);
      yh[f] = __builtin_amdgcn_mfma_f32_16x16x32_bf16(pf, vh,   yh[f], 0, 0, 0);
      y2[f] = __builtin_amdgcn_mfma_f32_16x16x32_bf16(pf, ones, y2[f], 0, 0, 0);
    }
  }

  // merge the 4 key quarters (R0 epilogue, unchanged)
  if (l16 == 0) {
#pragma unroll
    for (int f = 0; f < 4; ++f)
#pragma unroll
      for (int r = 0; r < 4; ++r)
        smL[wv][f * 16 + quad * 4 + r] = y2[f][r];   // cols identical
  }
  if (wv > 0) {
    int pi = wv - 1;
#pragma unroll
    for (int f = 0; f < 4; ++f)
#pragma unroll
      for (int r = 0; r < 4; ++r) {
        int lr = f * 16 + quad * 4 + r;
        smY[pi][lr][l16] = ya[f][r];
        smY[pi][lr][16 + l16] = yh[f][r];
      }
  }
  __syncthreads();
  if (wv == 0) {
#pragma unroll
    for (int f = 0; f < 4; ++f)
#pragma unroll
      for (int r = 0; r < 4; ++r) {
        int lr = f * 16 + quad * 4 + r;
        float a0 = ya[f][r] + smY[0][lr][l16] + smY[1][lr][l16] + smY[2][lr][l16];
        float a1 = yh[f][r] + smY[0][lr][16 + l16] + smY[1][lr][16 + l16] + smY[2][lr][16 + l16];
        float L = smL[0][lr] + smL[1][lr] + smL[2][lr] + smL[3][lr];
        float inv = 1.f / L;
        size_t rw = (size_t)bz * HW + qrow0 + lr;
        Y[rw * C2 + l16] = a0 * inv;
        Y[rw * C2 + 16 + l16] = a1 * inv;
      }
  }
}

// ---------------------------------------------------------------------------
// Kernel 3: output conv (32->64) + bias + residual — EXACT R4 version
// (best measured; R21 LDS staging regressed). cog split x8, 2048 blocks.
// ---------------------------------------------------------------------------
__global__ __launch_bounds__(256) void conv_out_kern(
    const float* __restrict__ Y, const float* __restrict__ x,
    const float* __restrict__ w, const float* __restrict__ bias,
    float* __restrict__ out) {
  int p = blockIdx.x * 256 + threadIdx.x;
  int cog = blockIdx.y, bz = blockIdx.z;    // cog 0..7 -> channels cog*8..+7
  const float* xb = x + (size_t)bz * Cin * HW + p;
  float xr[8];
#pragma unroll
  for (int i = 0; i < 8; ++i)               // residual loads in flight
    xr[i] = xb[(size_t)(cog * 8 + i) * HW];
  float y[C2];
  const float4* yp4 = (const float4*)(Y + ((size_t)bz * HW + p) * C2);
#pragma unroll
  for (int i = 0; i < 8; ++i) {
    float4 t = yp4[i];
    y[4 * i] = t.x; y[4 * i + 1] = t.y; y[4 * i + 2] = t.z; y[4 * i + 3] = t.w;
  }
  float* ob = out + (size_t)bz * Cin * HW + p;
#pragma unroll
  for (int i = 0; i < 8; ++i) {
    int co = cog * 8 + i;
    float s = bias[co];
#pragma unroll
    for (int o = 0; o < C2; ++o) s = fmaf(w[co * C2 + o], y[o], s);  // s_load
    ob[(size_t)co * HW] = s + xr[i];
  }
}

// ---------------------------------------------------------------------------
extern "C" void kernel_launch(void* const* d_in, const int* in_sizes, int n_in,
                              void* d_out, int out_size, void* d_ws, size_t ws_size,
                              hipStream_t stream) {
  const float* x       = (const float*)d_in[0];
  const float* w_theta = (const float*)d_in[1];
  const float* b_theta = (const float*)d_in[2];
  const float* w_phi   = (const float*)d_in[3];
  const float* b_phi   = (const float*)d_in[4];
  const float* w_g     = (const float*)d_in[5];
  const float* b_g     = (const float*)d_in[6];
  const float* w_out   = (const float*)d_in[7];
  const float* b_out   = (const float*)d_in[8];
  float* out = (float*)d_out;

  float* Yws = (float*)d_ws;                                   // 8 MB fp32
  unsigned short* Qb = (unsigned short*)(Yws + (size_t)4 * HW * C2);
  unsigned short* Kb = Qb + (size_t)4 * HW * C2;
  unsigned short* Vt = Kb + (size_t)4 * HW4 * C2;
  float* wAll = (float*)(Vt + (size_t)4 * HW4 * C2);           // 6144 f
  float* bAll = wAll + 6144;                                   // 96 f

  repack_w_kern<<<25, 256, 0, stream>>>(w_theta, b_theta, w_phi, b_phi,
                                        w_g, b_g, wAll, bAll);
  conv_qkv_kern<<<dim3(64, 8, 4), 256, 0, stream>>>(x, wAll, bAll, Qb, Kb, Vt);
  attn_mfma_kern<<<dim3(HW / 64, 4), 256, 0, stream>>>(Qb, Kb, Vt, Yws);
  conv_out_kern<<<dim3(64, 8, 4), 256, 0, stream>>>(Yws, x, w_out, b_out, out);
}

// Round 15
// 151.310 us; speedup vs baseline: 1.0159x; 1.0085x over previous
//
#include <hip/hip_runtime.h>

#define HW    16384   // 128*128
#define Wh    128
#define Cin   64
#define C2    32
#define HW4   4096    // 64*64

typedef short short8 __attribute__((ext_vector_type(8)));     // 8 bf16 = 4 VGPRs
typedef float float4v __attribute__((ext_vector_type(4)));
typedef unsigned uint4v __attribute__((ext_vector_type(4)));

#define LOG2E 1.44269504f
#define OFFE  43.2808512f   // 30*log2(e): exp(s-30) == exp2(s*log2e - OFFE)

__device__ __forceinline__ unsigned pack2bf16(float lo, float hi) {
  unsigned ul = __builtin_bit_cast(unsigned, lo);
  unsigned uh = __builtin_bit_cast(unsigned, hi);
  ul = (ul + 0x7fffu + ((ul >> 16) & 1u)) >> 16;
  uh = (uh + 0x7fffu + ((uh >> 16) & 1u)) & 0xffff0000u;
  return ul | uh;
}
__device__ __forceinline__ unsigned short f2bf(float f) {
  unsigned u = __builtin_bit_cast(unsigned, f);
  return (unsigned short)((u + 0x7fffu + ((u >> 16) & 1u)) >> 16);
}
// RTZ-truncate two fp32 to bf16, lo in [15:0], hi in [31:16]
__device__ __forceinline__ unsigned packtrunc(float lo, float hi) {
  return __builtin_amdgcn_perm(__builtin_bit_cast(unsigned, hi),
                               __builtin_bit_cast(unsigned, lo), 0x07060302u);
}

// ---------------------------------------------------------------------------
// Kernel 1: FUSED theta+phi+g conv (+2x2 maxpool) — R29: REPACK FOLDED IN.
// R28 post-mortem: conv_qkv occupancy-doubling neutral -> it's near its
// issue floor; residual is dominated by fixed harness overhead (~11 reset
// memset dispatches/iter + gaps, F ~= 75-85 µs). Remaining controllable
// dispatch: repack_kern. Folded BITWISE-IDENTICALLY: raw wt/wp/wg read via
// the same uniform->s_load path; theta weights scaled in-kernel with
// fmaf(wt[..]*LOG2E, xv, acc) — the v_mul produces the exact fp32 value
// repack stored, fmaf chain unchanged; bias bt*LOG2E at init (same op).
// Cost ~512 v_mul/thread (~+1.7 µs, VALU); saves repack kernel + 1 gap.
// V store TILE-MAJOR (R24 layout, the +11 µs attn win).
// ---------------------------------------------------------------------------
__global__ __launch_bounds__(256) void conv_qkv_kern(
    const float* __restrict__ x,
    const float* __restrict__ wt, const float* __restrict__ bt,
    const float* __restrict__ wp, const float* __restrict__ bp,
    const float* __restrict__ wg, const float* __restrict__ bg,
    unsigned short* __restrict__ Q, unsigned short* __restrict__ K,
    unsigned short* __restrict__ Vt) {
  __shared__ float smX[2][8][256];               // 16 KB, double-buffered
  __shared__ unsigned short smV[8][64];          // 1 KB
  int tid = threadIdx.x;
  int og = blockIdx.y, bz = blockIdx.z;
  int pxbase = blockIdx.x * 2 * Wh;              // full-res rows 2i, 2i+1
  int jloc = tid >> 2;                           // pooled col 0..63
  int rpar = (tid >> 1) & 1, cpar = tid & 1;
  int myPx = rpar * Wh + 2 * jloc + cpar;        // local pixel 0..255
  const float* xb = x + (size_t)bz * Cin * HW + pxbase;
  const float* wts = wt + (size_t)og * 8 * Cin;  // uniform -> s_load
  const float* wps = wp + (size_t)og * 8 * Cin;
  const float* wgs = wg + (size_t)og * 8 * Cin;

  // stage chunk: 512 float4 = 256 threads x 2; ch = f>>6, p4 = f&63
  auto stage = [&](int cb8, int buf) {
#pragma unroll
    for (int u = 0; u < 2; ++u) {
      int f = u * 256 + tid;
      int ch = f >> 6, p4 = f & 63;
      *(float4*)&smX[buf][ch][p4 * 4] =
          *(const float4*)(xb + (size_t)(cb8 * 8 + ch) * HW + p4 * 4);
    }
  };

  // acc[0..7]=theta (pre-scaled by LOG2E, same op repack did),
  // acc[8..15]=phi, acc[16..23]=g
  float acc[24];
#pragma unroll
  for (int k = 0; k < 8; ++k) {
    acc[k] = bt[og * 8 + k] * LOG2E;             // == repack's bAll value
    acc[8 + k] = bp[og * 8 + k];
    acc[16 + k] = bg[og * 8 + k];
  }

  stage(0, 0);
  __syncthreads();
  for (int cb8 = 0; cb8 < 8; ++cb8) {
    if (cb8 < 7) stage(cb8 + 1, (cb8 + 1) & 1);  // loads fly over compute
    float xv[8];
#pragma unroll
    for (int u = 0; u < 8; ++u) xv[u] = smX[cb8 & 1][u][myPx];
#pragma unroll
    for (int u = 0; u < 8; ++u) {
      int ch = cb8 * 8 + u;
#pragma unroll
      for (int k = 0; k < 8; ++k) {
        // wt*LOG2E: v_mul emits the exact fp32 repack stored -> fmaf chain
        // bitwise-identical to the repacked-weight version.
        acc[k]      = fmaf(wts[k * Cin + ch] * LOG2E, xv[u], acc[k]);
        acc[8 + k]  = fmaf(wps[k * Cin + ch], xv[u], acc[8 + k]);
        acc[16 + k] = fmaf(wgs[k * Cin + ch], xv[u], acc[16 + k]);
      }
    }
    __syncthreads();                             // staged buf ready for next
  }

  int pp = blockIdx.x * 64 + jloc;               // global pooled pixel
  int p = pxbase + myPx;                         // global full-res pixel
  // theta -> Q
  {
    uint4 up;
    up.x = pack2bf16(acc[0], acc[1]); up.y = pack2bf16(acc[2], acc[3]);
    up.z = pack2bf16(acc[4], acc[5]); up.w = pack2bf16(acc[6], acc[7]);
    *(uint4*)(Q + ((size_t)bz * HW + p) * C2 + og * 8) = up;
  }
  // 2x2 maxpool across lane-mates {4j..4j+3}
  float aP[8], aG[8];
#pragma unroll
  for (int o = 0; o < 8; ++o) {
    float vp = acc[8 + o], vg = acc[16 + o];
    vp = fmaxf(vp, __shfl_xor(vp, 1)); vp = fmaxf(vp, __shfl_xor(vp, 2));
    vg = fmaxf(vg, __shfl_xor(vg, 1)); vg = fmaxf(vg, __shfl_xor(vg, 2));
    aP[o] = vp; aG[o] = vg;
  }
  if ((tid & 3) == 0) {
    int loc = pp & 31, tile = pp >> 5;
    int prow = ((loc & 4) << 2) + ((loc >> 3) << 2) + (loc & 3);   // S^T perm
    uint4 up;
    up.x = pack2bf16(aP[0], aP[1]); up.y = pack2bf16(aP[2], aP[3]);
    up.z = pack2bf16(aP[4], aP[5]); up.w = pack2bf16(aP[6], aP[7]);
    *(uint4*)(K + ((size_t)bz * HW4 + tile * 32 + prow) * C2 + og * 8) = up;
#pragma unroll
    for (int o = 0; o < 8; ++o) smV[o][tid >> 2] = f2bf(aG[o]);
  }
  __syncthreads();
  // V store, TILE-MAJOR: Vt[bz][tile][ch][kin]. thread t -> ch t>>5,
  // keys 2*(t&31), 2*(t&31)+1 (one dword, same tile). Wave = two 128 B
  // segments -> coalesced.
  {
    int ch = tid >> 5, idx = tid & 31;
    unsigned v = ((unsigned*)smV)[ch * 32 + idx];
    int tile = blockIdx.x * 2 + (idx >> 4);      // key64 = 2*idx
    int kin = (2 * idx) & 31;
    *(unsigned*)(Vt + (size_t)bz * C2 * HW4 + (size_t)tile * (C2 * 32) +
                 (size_t)(og * 8 + ch) * 32 + kin) = v;
  }
}

// ---------------------------------------------------------------------------
// Kernel 2: MFMA flash attention — EXACT R24 form (best measured: 48.2 µs).
// attn surgery closed: loads 512->1024 hurts 1.6x (R25), 512->256 neutral
// (R27), waves 2/4/8 all equal (R27/R24/R26), 6 scheduling probes neutral.
// Tile-major V (the one real win, +11 µs) retained.
// ---------------------------------------------------------------------------
__global__ __launch_bounds__(256, 4) void attn_mfma_kern(
    const unsigned short* __restrict__ Qb, const unsigned short* __restrict__ Kb,
    const unsigned short* __restrict__ Vt, float* __restrict__ Y) {
  __shared__ float smY[3][64][33];   // 25.3 KB
  __shared__ float smL[4][64];       // 1 KB
  int lane = threadIdx.x & 63;
  int wv = threadIdx.x >> 6;
  int quad = lane >> 4, l16 = lane & 15;
  int bz = blockIdx.y;
  int qrow0 = blockIdx.x * 64;

  short8 qf[4];
#pragma unroll
  for (int f = 0; f < 4; ++f)
    qf[f] = *(const short8*)(Qb + ((size_t)bz * HW + qrow0 + f * 16 + l16) * C2 + quad * 8);
  const unsigned short* kb = Kb + ((size_t)bz * HW4 + wv * 1024) * C2;
  // wave wv's quarter = tiles wv*32 .. wv*32+31; one tile = C2*32 = 1024 shorts
  const unsigned short* vb = Vt + (size_t)bz * C2 * HW4 + (size_t)(wv * 32) * 1024;

  short8 ones;
#pragma unroll
  for (int i = 0; i < 8; ++i) ones[i] = (short)0x3F80;  // bf16 1.0

  float4v z = {0.f, 0.f, 0.f, 0.f};
  float4v ya[4] = {z, z, z, z};   // y cols l16 (ch 0..15)
  float4v yh[4] = {z, z, z, z};   // y cols 16+l16
  float4v y2[4] = {z, z, z, z};   // row sums l (ones-MFMA)
  float4v moff = {-OFFE, -OFFE, -OFFE, -OFFE};

  for (int t = 0; t < 32; ++t) {
    const unsigned short* kt = kb + (size_t)t * 32 * C2;
    const unsigned short* vt = vb + (size_t)t * 1024;
    short8 ka = *(const short8*)(kt + (size_t)l16 * C2 + quad * 8);
    short8 kh = *(const short8*)(kt + (size_t)(16 + l16) * C2 + quad * 8);
    short8 va = *(const short8*)(vt + l16 * 32 + quad * 8);          // 1 KB contig
    short8 vh = *(const short8*)(vt + (16 + l16) * 32 + quad * 8);   // next 1 KB
#pragma unroll
    for (int f = 0; f < 4; ++f) {
      float4v sa = __builtin_amdgcn_mfma_f32_16x16x32_bf16(ka, qf[f], moff, 0, 0, 0);
      float4v sh = __builtin_amdgcn_mfma_f32_16x16x32_bf16(kh, qf[f], moff, 0, 0, 0);
      float e0 = __builtin_amdgcn_exp2f(sa[0]), e1 = __builtin_amdgcn_exp2f(sa[1]);
      float e2 = __builtin_amdgcn_exp2f(sa[2]), e3 = __builtin_amdgcn_exp2f(sa[3]);
      float g0 = __builtin_amdgcn_exp2f(sh[0]), g1 = __builtin_amdgcn_exp2f(sh[1]);
      float g2 = __builtin_amdgcn_exp2f(sh[2]), g3 = __builtin_amdgcn_exp2f(sh[3]);
      uint4v d = {packtrunc(e0, e1), packtrunc(e2, e3),
                  packtrunc(g0, g1), packtrunc(g2, g3)};
      short8 pf = __builtin_bit_cast(short8, d);
      ya[f] = __builtin_amdgcn_mfma_f32_16x16x32_bf16(pf, va,   ya[f], 0, 0, 0);
      yh[f] = __builtin_amdgcn_mfma_f32_16x16x32_bf16(pf, vh,   yh[f], 0, 0, 0);
      y2[f] = __builtin_amdgcn_mfma_f32_16x16x32_bf16(pf, ones, y2[f], 0, 0, 0);
    }
  }

  // merge the 4 key quarters (R0 epilogue, unchanged)
  if (l16 == 0) {
#pragma unroll
    for (int f = 0; f < 4; ++f)
#pragma unroll
      for (int r = 0; r < 4; ++r)
        smL[wv][f * 16 + quad * 4 + r] = y2[f][r];   // cols identical
  }
  if (wv > 0) {
    int pi = wv - 1;
#pragma unroll
    for (int f = 0; f < 4; ++f)
#pragma unroll
      for (int r = 0; r < 4; ++r) {
        int lr = f * 16 + quad * 4 + r;
        smY[pi][lr][l16] = ya[f][r];
        smY[pi][lr][16 + l16] = yh[f][r];
      }
  }
  __syncthreads();
  if (wv == 0) {
#pragma unroll
    for (int f = 0; f < 4; ++f)
#pragma unroll
      for (int r = 0; r < 4; ++r) {
        int lr = f * 16 + quad * 4 + r;
        float a0 = ya[f][r] + smY[0][lr][l16] + smY[1][lr][l16] + smY[2][lr][l16];
        float a1 = yh[f][r] + smY[0][lr][16 + l16] + smY[1][lr][16 + l16] + smY[2][lr][16 + l16];
        float L = smL[0][lr] + smL[1][lr] + smL[2][lr] + smL[3][lr];
        float inv = 1.f / L;
        size_t rw = (size_t)bz * HW + qrow0 + lr;
        Y[rw * C2 + l16] = a0 * inv;
        Y[rw * C2 + 16 + l16] = a1 * inv;
      }
  }
}

// ---------------------------------------------------------------------------
// Kernel 3: output conv (32->64) + bias + residual — EXACT R4 version
// (best measured; R21 LDS staging regressed). cog split x8, 2048 blocks.
// ---------------------------------------------------------------------------
__global__ __launch_bounds__(256) void conv_out_kern(
    const float* __restrict__ Y, const float* __restrict__ x,
    const float* __restrict__ w, const float* __restrict__ bias,
    float* __restrict__ out) {
  int p = blockIdx.x * 256 + threadIdx.x;
  int cog = blockIdx.y, bz = blockIdx.z;    // cog 0..7 -> channels cog*8..+7
  const float* xb = x + (size_t)bz * Cin * HW + p;
  float xr[8];
#pragma unroll
  for (int i = 0; i < 8; ++i)               // residual loads in flight
    xr[i] = xb[(size_t)(cog * 8 + i) * HW];
  float y[C2];
  const float4* yp4 = (const float4*)(Y + ((size_t)bz * HW + p) * C2);
#pragma unroll
  for (int i = 0; i < 8; ++i) {
    float4 t = yp4[i];
    y[4 * i] = t.x; y[4 * i + 1] = t.y; y[4 * i + 2] = t.z; y[4 * i + 3] = t.w;
  }
  float* ob = out + (size_t)bz * Cin * HW + p;
#pragma unroll
  for (int i = 0; i < 8; ++i) {
    int co = cog * 8 + i;
    float s = bias[co];
#pragma unroll
    for (int o = 0; o < C2; ++o) s = fmaf(w[co * C2 + o], y[o], s);  // s_load
    ob[(size_t)co * HW] = s + xr[i];
  }
}

// ---------------------------------------------------------------------------
extern "C" void kernel_launch(void* const* d_in, const int* in_sizes, int n_in,
                              void* d_out, int out_size, void* d_ws, size_t ws_size,
                              hipStream_t stream) {
  const float* x       = (const float*)d_in[0];
  const float* w_theta = (const float*)d_in[1];
  const float* b_theta = (const float*)d_in[2];
  const float* w_phi   = (const float*)d_in[3];
  const float* b_phi   = (const float*)d_in[4];
  const float* w_g     = (const float*)d_in[5];
  const float* b_g     = (const float*)d_in[6];
  const float* w_out   = (const float*)d_in[7];
  const float* b_out   = (const float*)d_in[8];
  float* out = (float*)d_out;

  float* Yws = (float*)d_ws;                                   // 8 MB fp32
  unsigned short* Qb = (unsigned short*)(Yws + (size_t)4 * HW * C2);
  unsigned short* Kb = Qb + (size_t)4 * HW * C2;
  unsigned short* Vt = Kb + (size_t)4 * HW4 * C2;

  conv_qkv_kern<<<dim3(64, 4, 4), 256, 0, stream>>>(
      x, w_theta, b_theta, w_phi, b_phi, w_g, b_g, Qb, Kb, Vt);
  attn_mfma_kern<<<dim3(HW / 64, 4), 256, 0, stream>>>(Qb, Kb, Vt, Yws);
  conv_out_kern<<<dim3(64, 8, 4), 256, 0, stream>>>(Yws, x, w_out, b_out, out);
}